// Round 8
// baseline (97.491 us; speedup 1.0000x reference)
//
#include <hip/hip_runtime.h>
#include <hip/hip_bf16.h>
#include <math.h>

#define B_ 256
#define G_ 4000
#define P_ 128
#define D_ 12000
#define H_ 64
#define O_ 16
#define GH_ 128
#define CH_ 8
#define C_ 5
#define K_ 3
#define EPS_ 1e-5f
#define CAP_ 640      // per-pathway compacted row capacity (n_p ~ 400 +- 20)
#define TILE_ 512     // gene tile staged in LDS (expert)

__device__ __forceinline__ float bf_lo(unsigned int u) {
  return __uint_as_float(u << 16);
}
__device__ __forceinline__ float bf_hi(unsigned int u) {
  return __uint_as_float(u & 0xffff0000u);
}

// ---------------------------------------------------------------------------
// K1: fused input-side preprocessing.
//   blocks [0,128):    pathway compaction: ballot+prefix scan of gene_mask
//                      column p -> gindex[p][i]=g, cnt[p], AND dense bf16
//                      weight planes wcomp[p][omic][i][0..63].
//   blocks [128,384):  gate MLP per sample (xs-staged GEMM1, GEMM2,
//                      wave-parallel top-3 + sigmoid) -> out_gw, sel.
// ---------------------------------------------------------------------------
union SMemPre {
  struct { int wsum[8]; int cg[512]; } comp;
  struct {
    float xs[G_];
    float part[4][GH_];
    float hid[GH_];
    float logitS[P_];
    int   s_idx[K_];
    float s_val[K_];
  } gate;
};

__global__ __launch_bounds__(512) void k_pre(const float* __restrict__ gene_mask,
                                             const float* __restrict__ x_rna,
                                             const float* __restrict__ gw1,
                                             const float* __restrict__ gb1,
                                             const float* __restrict__ gw2,
                                             const float* __restrict__ gb2,
                                             const float* __restrict__ W1,
                                             int* __restrict__ cnt,
                                             int* __restrict__ gindex,
                                             unsigned short* __restrict__ wcomp,
                                             float* __restrict__ out_gw,
                                             int* __restrict__ sel_idx,
                                             float* __restrict__ sel_w) {
  __shared__ SMemPre sm;
  const int t = threadIdx.x;

  if (blockIdx.x < P_) {
    // ---- compaction + bf16 plane build, pathway p ----
    int p = blockIdx.x;
    int lane = t & 63, w = t >> 6;
    int base = 0;
    for (int ch = 0; ch < (G_ + 511) / 512; ++ch) {
      int g = ch * 512 + t;
      bool act = (g < G_) && (gene_mask[(size_t)g * P_ + p] != 0.0f);
      unsigned long long bal = __ballot(act);
      int rk = __popcll(bal & ((1ull << lane) - 1ull));
      if (lane == 0) sm.comp.wsum[w] = __popcll(bal);
      __syncthreads();
      int wbase = 0, nact = 0;
#pragma unroll
      for (int i = 0; i < 8; ++i) {
        int v = sm.comp.wsum[i];
        if (i < w) wbase += v;
        nact += v;
      }
      if (act) sm.comp.cg[wbase + rk] = g;
      __syncthreads();
      // copy the nact active rows (3 omic planes x 64 h) as bf16
      for (int idx = t; idx < nact * 192; idx += 512) {
        int a = idx / 192;
        int r = idx - a * 192;
        int o = r >> 6, h = r & 63;
        int gg = sm.comp.cg[a];
        int gi = base + a;
        if (r == 0) gindex[(size_t)p * G_ + gi] = gg;
        if (gi < CAP_) {
          float f = W1[((size_t)p * D_ + (size_t)o * G_ + gg) * H_ + h];
          __hip_bfloat16 bv = __float2bfloat16(f);
          wcomp[((size_t)(p * 3 + o) * CAP_ + gi) * H_ + h] =
              *(unsigned short*)&bv;
        }
      }
      base += nact;
      __syncthreads();
    }
    if (t == 0) cnt[p] = base;
    return;
  }

  // ---- gate MLP for sample b ----
  int b = blockIdx.x - P_;
  int j = t & 127;                  // hidden / logit unit
  int slice = t >> 7;               // 0..3 g-slice

  for (int g = t; g < G_; g += 512) sm.gate.xs[g] = x_rna[(size_t)b * G_ + g];
  __syncthreads();

  float acc = 0.f;
  int g0 = slice * (G_ / 4), g1 = g0 + (G_ / 4);
  for (int g = g0; g < g1; ++g)
    acc = fmaf(sm.gate.xs[g], gw1[(size_t)g * GH_ + j], acc);
  sm.gate.part[slice][j] = acc;
  __syncthreads();

  if (t < GH_) {
    float h = sm.gate.part[0][t] + sm.gate.part[1][t] + sm.gate.part[2][t] +
              sm.gate.part[3][t] + gb1[t];
    sm.gate.hid[t] = fmaxf(h, 0.f);
  }
  __syncthreads();

  if (t < P_) {
    float acc2 = gb2[t];
    for (int jj = 0; jj < GH_; ++jj)
      acc2 = fmaf(sm.gate.hid[jj], gw2[(size_t)jj * P_ + t], acc2);
    sm.gate.logitS[t] = acc2;
  }
  __syncthreads();

  if (t < 64) {
    float v0 = sm.gate.logitS[t], v1 = sm.gate.logitS[t + 64];
    int i0 = t, i1 = t + 64;
    for (int k = 0; k < K_; ++k) {
      float v; int i;
      if (v0 > v1 || (v0 == v1 && i0 < i1)) { v = v0; i = i0; }
      else                                  { v = v1; i = i1; }
      for (int sft = 1; sft < 64; sft <<= 1) {
        float ov = __shfl_xor(v, sft);
        int   oi = __shfl_xor(i, sft);
        if (ov > v || (ov == v && oi < i)) { v = ov; i = oi; }
      }
      if (t == 0) {
        float w = 1.f / (1.f + expf(-v));
        sm.gate.s_idx[k] = i; sm.gate.s_val[k] = w;
        sel_idx[b * K_ + k] = i;
        sel_w[b * K_ + k] = w;
      }
      if (i0 == i) v0 = -INFINITY;
      if (i1 == i) v1 = -INFINITY;
    }
  }
  __syncthreads();

  if (t < P_) {
    float gwv = 0.f;
    for (int k = 0; k < K_; ++k)
      if (sm.gate.s_idx[k] == t) gwv = sm.gate.s_val[k];
    out_gw[(size_t)b * P_ + t] = gwv;
  }
}

// ---------------------------------------------------------------------------
// K2: expert compute, one block (8 waves) per (sample, pathway) selection
// (R5 structure). x values gathered to LDS; weights read from the dense bf16
// planes: each wave instruction is a fully-contiguous 512B load (4 rows x
// 128B), vs the old 4-segment scattered float4 gathers. Per-wave partials
// to LDS part[32][64], reduce, BN + ReLU + W2 -> eo[bk].
// ---------------------------------------------------------------------------
__global__ __launch_bounds__(512) void k_expert(const float* __restrict__ xr,
                                                const float* __restrict__ xc,
                                                const float* __restrict__ xm,
                                                const float* __restrict__ W1,
                                                const float* __restrict__ b1,
                                                const float* __restrict__ bn_g,
                                                const float* __restrict__ bn_b,
                                                const float* __restrict__ bn_m,
                                                const float* __restrict__ bn_v,
                                                const float* __restrict__ W2,
                                                const float* __restrict__ b2,
                                                const int* __restrict__ cnt,
                                                const int* __restrict__ gindex,
                                                const unsigned short* __restrict__ wcomp,
                                                const int* __restrict__ sel_idx,
                                                float* __restrict__ eo) {
  int bk = blockIdx.x;              // 768 blocks
  int b = bk / K_;
  int t = threadIdx.x;
  int w = t >> 6;                   // wave 0..7
  int lane = t & 63;
  int j = lane >> 4;                // gene subgroup 0..3
  int hq = lane & 15;               // h-quad: h = hq*4..hq*4+3
  int p = sel_idx[bk];
  int n = cnt[p];
  const int* gp = gindex + (size_t)p * G_;
  const unsigned short* Wp = wcomp + (size_t)(p * 3) * CAP_ * H_;
  const float* xrb = xr + (size_t)b * G_;
  const float* xcb = xc + (size_t)b * G_;
  const float* xmb = xm + (size_t)b * G_;

  __shared__ int   glist[TILE_];
  __shared__ float xv0[TILE_], xv1[TILE_], xv2[TILE_];
  __shared__ float part[32][H_];    // 8 KB
  __shared__ float hs[H_];

  float a0 = 0.f, a1 = 0.f, a2 = 0.f, a3 = 0.f;

  for (int t0 = 0; t0 < n; t0 += TILE_) {
    int m = n - t0; if (m > TILE_) m = TILE_;
    __syncthreads();
    for (int i = t; i < m; i += 512) {
      int g = gp[t0 + i];
      glist[i] = g;
      xv0[i] = xrb[g]; xv1[i] = xcb[g]; xv2[i] = xmb[g];
    }
    __syncthreads();
    int mfast = CAP_ - t0;
    if (mfast > m) mfast = m;
    if (mfast < 0) mfast = 0;
    for (int i0 = w * 4 + j; i0 < mfast; i0 += 32) {
      size_t off = (size_t)(t0 + i0) * H_ + hq * 4;
      uint2 u0 = *(const uint2*)(Wp + off);
      uint2 u1 = *(const uint2*)(Wp + (size_t)CAP_ * H_ + off);
      uint2 u2 = *(const uint2*)(Wp + (size_t)2 * CAP_ * H_ + off);
      float x0 = xv0[i0], x1 = xv1[i0], x2 = xv2[i0];
      a0 = fmaf(x0, bf_lo(u0.x), a0); a1 = fmaf(x0, bf_hi(u0.x), a1);
      a2 = fmaf(x0, bf_lo(u0.y), a2); a3 = fmaf(x0, bf_hi(u0.y), a3);
      a0 = fmaf(x1, bf_lo(u1.x), a0); a1 = fmaf(x1, bf_hi(u1.x), a1);
      a2 = fmaf(x1, bf_lo(u1.y), a2); a3 = fmaf(x1, bf_hi(u1.y), a3);
      a0 = fmaf(x2, bf_lo(u2.x), a0); a1 = fmaf(x2, bf_hi(u2.x), a1);
      a2 = fmaf(x2, bf_lo(u2.y), a2); a3 = fmaf(x2, bf_hi(u2.y), a3);
    }
    if (mfast < m) {
      // overflow tail (n > CAP_, not expected in practice): direct f32 gather
      const float* W1p = W1 + (size_t)p * D_ * H_;
      for (int i0 = w * 4 + j; i0 < m; i0 += 32) {
        if (i0 < mfast) continue;
        int g = glist[i0];
        const float* r = W1p + (size_t)g * H_ + hq * 4;
        float4 w0 = *(const float4*)r;
        float4 w1 = *(const float4*)(r + (size_t)G_ * H_);
        float4 w2 = *(const float4*)(r + (size_t)(2 * G_) * H_);
        float x0 = xv0[i0], x1 = xv1[i0], x2 = xv2[i0];
        a0 = fmaf(x0, w0.x, a0); a1 = fmaf(x0, w0.y, a1);
        a2 = fmaf(x0, w0.z, a2); a3 = fmaf(x0, w0.w, a3);
        a0 = fmaf(x1, w1.x, a0); a1 = fmaf(x1, w1.y, a1);
        a2 = fmaf(x1, w1.z, a2); a3 = fmaf(x1, w1.w, a3);
        a0 = fmaf(x2, w2.x, a0); a1 = fmaf(x2, w2.y, a1);
        a2 = fmaf(x2, w2.z, a2); a3 = fmaf(x2, w2.w, a3);
      }
    }
  }
  {
    float4 av = {a0, a1, a2, a3};
    *(float4*)&part[w * 4 + j][hq * 4] = av;
  }
  __syncthreads();

  if (t < H_) {
    float s = 0.f;
#pragma unroll
    for (int ss = 0; ss < 32; ++ss) s += part[ss][t];
    int ph = p * H_ + t;
    s += b1[ph];
    float hn = (s - bn_m[ph]) * (bn_g[ph] * rsqrtf(bn_v[ph] + EPS_)) + bn_b[ph];
    hs[t] = fmaxf(hn, 0.f);
  }
  __syncthreads();

  if (t < O_) {
    const float* W2p = W2 + (size_t)p * H_ * O_;
    float o = b2[p * O_ + t];
    for (int jj = 0; jj < H_; ++jj) o = fmaf(hs[jj], W2p[jj * O_ + t], o);
    eo[(size_t)bk * O_ + t] = o;
  }
}

// ---------------------------------------------------------------------------
// K3: weighted combine of the K expert outputs + classifier MLP.
// ---------------------------------------------------------------------------
__global__ __launch_bounds__(64) void k_final(const float* __restrict__ eo,
                                              const float* __restrict__ sel_w,
                                              const float* __restrict__ cw1,
                                              const float* __restrict__ cb1,
                                              const float* __restrict__ cw2,
                                              const float* __restrict__ cb2,
                                              float* __restrict__ out_logits) {
  int b = blockIdx.x * blockDim.x + threadIdx.x;
  if (b >= B_) return;
  float feat[O_];
  float w0 = sel_w[b * K_ + 0], w1 = sel_w[b * K_ + 1], w2 = sel_w[b * K_ + 2];
  const float* e0 = eo + (size_t)(b * K_ + 0) * O_;
  const float* e1 = eo + (size_t)(b * K_ + 1) * O_;
  const float* e2 = eo + (size_t)(b * K_ + 2) * O_;
  for (int o = 0; o < O_; ++o)
    feat[o] = w0 * e0[o] + w1 * e1[o] + w2 * e2[o];

  float ch[CH_];
  for (int jj = 0; jj < CH_; ++jj) {
    float a = cb1[jj];
    for (int o = 0; o < O_; ++o) a = fmaf(feat[o], cw1[o * CH_ + jj], a);
    ch[jj] = fmaxf(a, 0.f);
  }
  for (int c = 0; c < C_; ++c) {
    float a = cb2[c];
    for (int jj = 0; jj < CH_; ++jj) a = fmaf(ch[jj], cw2[jj * C_ + c], a);
    out_logits[(size_t)b * C_ + c] = a;
  }
}

// ---------------------------------------------------------------------------
extern "C" void kernel_launch(void* const* d_in, const int* in_sizes, int n_in,
                              void* d_out, int out_size, void* d_ws, size_t ws_size,
                              hipStream_t stream) {
  const float* x_rna    = (const float*)d_in[0];
  const float* x_cnv    = (const float*)d_in[1];
  const float* x_met    = (const float*)d_in[2];
  const float* gene_mask= (const float*)d_in[3];
  const float* gate_w1  = (const float*)d_in[4];
  const float* gate_b1  = (const float*)d_in[5];
  const float* gate_w2  = (const float*)d_in[6];
  const float* gate_b2  = (const float*)d_in[7];
  const float* W1       = (const float*)d_in[8];
  const float* b1       = (const float*)d_in[9];
  const float* bn_g     = (const float*)d_in[10];
  const float* bn_b     = (const float*)d_in[11];
  const float* bn_m     = (const float*)d_in[12];
  const float* bn_v     = (const float*)d_in[13];
  const float* W2       = (const float*)d_in[14];
  const float* b2       = (const float*)d_in[15];
  const float* cls_w1   = (const float*)d_in[16];
  const float* cls_b1   = (const float*)d_in[17];
  const float* cls_w2   = (const float*)d_in[18];
  const float* cls_b2   = (const float*)d_in[19];

  float* out_logits = (float*)d_out;                   // [B, C]
  float* out_gw     = (float*)d_out + (size_t)B_ * C_; // [B, P]

  // workspace layout (bytes)
  char* ws = (char*)d_ws;
  int*   cnt     = (int*)(ws + 0);                 // 512
  int*   gindex  = (int*)(ws + 512);               // 128*4000*4 = 2,048,000
  int*   sel_idx = (int*)(ws + 2048512);           // 3072
  float* sel_w   = (float*)(ws + 2051584);         // 3072
  float* eo      = (float*)(ws + 2054656);         // 49152
  unsigned short* wcomp = (unsigned short*)(ws + 2103808); // 128*3*640*64*2 = 31.5MB

  hipLaunchKernelGGL(k_pre, dim3(P_ + B_), dim3(512), 0, stream,
                     gene_mask, x_rna, gate_w1, gate_b1, gate_w2, gate_b2,
                     W1, cnt, gindex, wcomp, out_gw, sel_idx, sel_w);
  hipLaunchKernelGGL(k_expert, dim3(B_ * K_), dim3(512), 0, stream,
                     x_rna, x_cnv, x_met, W1, b1, bn_g, bn_b, bn_m, bn_v,
                     W2, b2, cnt, gindex, wcomp, sel_idx, eo);
  hipLaunchKernelGGL(k_final, dim3((B_ + 63) / 64), dim3(64), 0, stream,
                     eo, sel_w, cls_w1, cls_b1, cls_w2, cls_b2, out_logits);
}

// Round 9
// 84.396 us; speedup vs baseline: 1.1551x; 1.1551x over previous
//
#include <hip/hip_runtime.h>
#include <hip/hip_bf16.h>
#include <math.h>

#define B_ 256
#define G_ 4000
#define P_ 128
#define D_ 12000
#define H_ 64
#define O_ 16
#define GH_ 128
#define CH_ 8
#define C_ 5
#define K_ 3
#define EPS_ 1e-5f
#define CAP_ 640      // per-pathway compacted row capacity (n_p ~ 400 +- 20)
#define TILE_ 640     // gene tile staged in LDS (expert) — covers n<=CAP in 1 pass

__device__ __forceinline__ float bf_lo(unsigned int u) {
  return __uint_as_float(u << 16);
}
__device__ __forceinline__ float bf_hi(unsigned int u) {
  return __uint_as_float(u & 0xffff0000u);
}

// ---------------------------------------------------------------------------
// K1: fused preprocessing (R5 structure, proven).
//   blocks [0,128):    per-pathway active-gene compaction (8 waves, 2-pass)
//   blocks [128,384):  gate MLP per sample -> out_gw, sel_idx, sel_w
// ---------------------------------------------------------------------------
__global__ __launch_bounds__(512) void k_pre(const float* __restrict__ gene_mask,
                                             const float* __restrict__ x_rna,
                                             const float* __restrict__ gw1,
                                             const float* __restrict__ gb1,
                                             const float* __restrict__ gw2,
                                             const float* __restrict__ gb2,
                                             int* __restrict__ cnt,
                                             int* __restrict__ gindex,
                                             float* __restrict__ out_gw,
                                             int* __restrict__ sel_idx,
                                             float* __restrict__ sel_w) {
  int t = threadIdx.x;

  if (blockIdx.x < P_) {
    int p = blockIdx.x;
    int lane = t & 63;
    int w = t >> 6;
    __shared__ int wcnt[8];
    int* lp = gindex + (size_t)p * G_;
    const int per = (G_ + 7) / 8;   // 500
    int start = w * per;
    int end = start + per; if (end > G_) end = G_;

    int count = 0;
    for (int g0 = start; g0 < end; g0 += 64) {
      int g = g0 + lane;
      bool act = (g < end) && (gene_mask[(size_t)g * P_ + p] != 0.0f);
      count += __popcll(__ballot(act));
    }
    if (lane == 0) wcnt[w] = count;
    __syncthreads();
    if (t == 0) {
      int tot = 0;
      for (int i = 0; i < 8; ++i) tot += wcnt[i];
      cnt[p] = tot;
    }
    int base = 0;
    for (int i = 0; i < w; ++i) base += wcnt[i];
    for (int g0 = start; g0 < end; g0 += 64) {
      int g = g0 + lane;
      bool act = (g < end) && (gene_mask[(size_t)g * P_ + p] != 0.0f);
      unsigned long long bal = __ballot(act);
      int rank = __popcll(bal & ((1ull << lane) - 1ull));
      if (act) lp[base + rank] = g;
      base += __popcll(bal);
    }
    return;
  }

  // ---- gate MLP for sample b ----
  int b = blockIdx.x - P_;
  int j = t & 127;                  // hidden / logit unit
  int slice = t >> 7;               // 0..3 g-slice

  __shared__ float xs[G_];          // 16 KB
  __shared__ float part[4][GH_];
  __shared__ float hid[GH_];
  __shared__ float logitS[P_];
  __shared__ int   s_idx[K_];
  __shared__ float s_val[K_];

  for (int g = t; g < G_; g += 512) xs[g] = x_rna[(size_t)b * G_ + g];
  __syncthreads();

  float acc = 0.f;
  int g0 = slice * (G_ / 4), g1 = g0 + (G_ / 4);
  for (int g = g0; g < g1; ++g) acc = fmaf(xs[g], gw1[(size_t)g * GH_ + j], acc);
  part[slice][j] = acc;
  __syncthreads();

  if (t < GH_) {
    float h = part[0][t] + part[1][t] + part[2][t] + part[3][t] + gb1[t];
    hid[t] = fmaxf(h, 0.f);
  }
  __syncthreads();

  if (t < P_) {
    float acc2 = gb2[t];
    for (int jj = 0; jj < GH_; ++jj) acc2 = fmaf(hid[jj], gw2[(size_t)jj * P_ + t], acc2);
    logitS[t] = acc2;
  }
  __syncthreads();

  if (t < 64) {
    float v0 = logitS[t], v1 = logitS[t + 64];
    int i0 = t, i1 = t + 64;
    for (int k = 0; k < K_; ++k) {
      float v; int i;
      if (v0 > v1 || (v0 == v1 && i0 < i1)) { v = v0; i = i0; }
      else                                  { v = v1; i = i1; }
      for (int sft = 1; sft < 64; sft <<= 1) {
        float ov = __shfl_xor(v, sft);
        int   oi = __shfl_xor(i, sft);
        if (ov > v || (ov == v && oi < i)) { v = ov; i = oi; }
      }
      if (t == 0) {
        float w = 1.f / (1.f + expf(-v));
        s_idx[k] = i; s_val[k] = w;
        sel_idx[b * K_ + k] = i;
        sel_w[b * K_ + k] = w;
      }
      if (i0 == i) v0 = -INFINITY;
      if (i1 == i) v1 = -INFINITY;
    }
  }
  __syncthreads();

  if (t < P_) {
    float gwv = 0.f;
    for (int k = 0; k < K_; ++k) if (s_idx[k] == t) gwv = s_val[k];
    out_gw[(size_t)b * P_ + t] = gwv;
  }
}

// ---------------------------------------------------------------------------
// K2: wide W1 compaction to dense bf16 planes. 1024 blocks = (pathway p,
// row-chunk c of 8); 4 waves/block; one wave copies one (omic,row):
// 64-lane coalesced 256B fp32 read -> bf16 -> 128B contiguous write.
// wcomp layout: [p][omic][gi][h].
// ---------------------------------------------------------------------------
__global__ __launch_bounds__(256) void k_copy(const float* __restrict__ W1,
                                              const int* __restrict__ cnt,
                                              const int* __restrict__ gindex,
                                              unsigned short* __restrict__ wcomp) {
  int p = blockIdx.x >> 3;
  int c = blockIdx.x & 7;
  int n = cnt[p];
  if (n > CAP_) n = CAP_;           // overflow handled by expert's f32 tail
  int per = (n + 7) / 8;
  int r0 = c * per, r1 = r0 + per;
  if (r1 > n) r1 = n;
  if (r0 >= r1) return;
  int lane = threadIdx.x & 63;
  int w = threadIdx.x >> 6;         // 0..3
  const int* gp = gindex + (size_t)p * G_;

#pragma unroll
  for (int o = 0; o < 3; ++o) {
    const float* src = W1 + ((size_t)p * D_ + (size_t)o * G_) * H_;
    unsigned short* dst = wcomp + (size_t)(p * 3 + o) * CAP_ * H_;
    for (int gi = r0 + w; gi < r1; gi += 4) {
      int g = gp[gi];
      float f = src[(size_t)g * H_ + lane];
      __hip_bfloat16 bv = __float2bfloat16(f);
      dst[(size_t)gi * H_ + lane] = *(unsigned short*)&bv;
    }
  }
}

// ---------------------------------------------------------------------------
// K3: expert compute, one block (8 waves) per (sample, pathway) selection
// (R5 structure). x gathered to LDS; weights read from dense bf16 planes:
// each wave instruction is a fully-contiguous 512B load. Per-wave partials
// to LDS part[32][64], reduce, BN + ReLU + W2 -> eo[bk].
// ---------------------------------------------------------------------------
__global__ __launch_bounds__(512) void k_expert(const float* __restrict__ xr,
                                                const float* __restrict__ xc,
                                                const float* __restrict__ xm,
                                                const float* __restrict__ W1,
                                                const float* __restrict__ b1,
                                                const float* __restrict__ bn_g,
                                                const float* __restrict__ bn_b,
                                                const float* __restrict__ bn_m,
                                                const float* __restrict__ bn_v,
                                                const float* __restrict__ W2,
                                                const float* __restrict__ b2,
                                                const int* __restrict__ cnt,
                                                const int* __restrict__ gindex,
                                                const unsigned short* __restrict__ wcomp,
                                                const int* __restrict__ sel_idx,
                                                float* __restrict__ eo) {
  int bk = blockIdx.x;              // 768 blocks
  int b = bk / K_;
  int t = threadIdx.x;
  int w = t >> 6;                   // wave 0..7
  int lane = t & 63;
  int j = lane >> 4;                // gene subgroup 0..3
  int hq = lane & 15;               // h-quad: h = hq*4..hq*4+3
  int p = sel_idx[bk];
  int n = cnt[p];
  const int* gp = gindex + (size_t)p * G_;
  const unsigned short* Wp = wcomp + (size_t)(p * 3) * CAP_ * H_;
  const float* xrb = xr + (size_t)b * G_;
  const float* xcb = xc + (size_t)b * G_;
  const float* xmb = xm + (size_t)b * G_;

  __shared__ int   glist[TILE_];
  __shared__ float xv0[TILE_], xv1[TILE_], xv2[TILE_];
  __shared__ float part[32][H_];    // 8 KB
  __shared__ float hs[H_];

  float a0 = 0.f, a1 = 0.f, a2 = 0.f, a3 = 0.f;

  for (int t0 = 0; t0 < n; t0 += TILE_) {
    int m = n - t0; if (m > TILE_) m = TILE_;
    __syncthreads();
    for (int i = t; i < m; i += 512) {
      int g = gp[t0 + i];
      glist[i] = g;
      xv0[i] = xrb[g]; xv1[i] = xcb[g]; xv2[i] = xmb[g];
    }
    __syncthreads();
    int mfast = CAP_ - t0;
    if (mfast > m) mfast = m;
    if (mfast < 0) mfast = 0;
    for (int i0 = w * 4 + j; i0 < mfast; i0 += 32) {
      size_t off = (size_t)(t0 + i0) * H_ + hq * 4;
      uint2 u0 = *(const uint2*)(Wp + off);
      uint2 u1 = *(const uint2*)(Wp + (size_t)CAP_ * H_ + off);
      uint2 u2 = *(const uint2*)(Wp + (size_t)2 * CAP_ * H_ + off);
      float x0 = xv0[i0], x1 = xv1[i0], x2 = xv2[i0];
      a0 = fmaf(x0, bf_lo(u0.x), a0); a1 = fmaf(x0, bf_hi(u0.x), a1);
      a2 = fmaf(x0, bf_lo(u0.y), a2); a3 = fmaf(x0, bf_hi(u0.y), a3);
      a0 = fmaf(x1, bf_lo(u1.x), a0); a1 = fmaf(x1, bf_hi(u1.x), a1);
      a2 = fmaf(x1, bf_lo(u1.y), a2); a3 = fmaf(x1, bf_hi(u1.y), a3);
      a0 = fmaf(x2, bf_lo(u2.x), a0); a1 = fmaf(x2, bf_hi(u2.x), a1);
      a2 = fmaf(x2, bf_lo(u2.y), a2); a3 = fmaf(x2, bf_hi(u2.y), a3);
    }
    if (mfast < m) {
      // overflow tail (n > CAP_): direct f32 gather from original W1
      const float* W1p = W1 + (size_t)p * D_ * H_;
      for (int i0 = w * 4 + j; i0 < m; i0 += 32) {
        if (i0 < mfast) continue;
        int g = glist[i0];
        const float* r = W1p + (size_t)g * H_ + hq * 4;
        float4 w0 = *(const float4*)r;
        float4 w1 = *(const float4*)(r + (size_t)G_ * H_);
        float4 w2 = *(const float4*)(r + (size_t)(2 * G_) * H_);
        float x0 = xv0[i0], x1 = xv1[i0], x2 = xv2[i0];
        a0 = fmaf(x0, w0.x, a0); a1 = fmaf(x0, w0.y, a1);
        a2 = fmaf(x0, w0.z, a2); a3 = fmaf(x0, w0.w, a3);
        a0 = fmaf(x1, w1.x, a0); a1 = fmaf(x1, w1.y, a1);
        a2 = fmaf(x1, w1.z, a2); a3 = fmaf(x1, w1.w, a3);
        a0 = fmaf(x2, w2.x, a0); a1 = fmaf(x2, w2.y, a1);
        a2 = fmaf(x2, w2.z, a2); a3 = fmaf(x2, w2.w, a3);
      }
    }
  }
  {
    float4 av = {a0, a1, a2, a3};
    *(float4*)&part[w * 4 + j][hq * 4] = av;
  }
  __syncthreads();

  if (t < H_) {
    float s = 0.f;
#pragma unroll
    for (int ss = 0; ss < 32; ++ss) s += part[ss][t];
    int ph = p * H_ + t;
    s += b1[ph];
    float hn = (s - bn_m[ph]) * (bn_g[ph] * rsqrtf(bn_v[ph] + EPS_)) + bn_b[ph];
    hs[t] = fmaxf(hn, 0.f);
  }
  __syncthreads();

  if (t < O_) {
    const float* W2p = W2 + (size_t)p * H_ * O_;
    float o = b2[p * O_ + t];
    for (int jj = 0; jj < H_; ++jj) o = fmaf(hs[jj], W2p[jj * O_ + t], o);
    eo[(size_t)bk * O_ + t] = o;
  }
}

// ---------------------------------------------------------------------------
// K4: weighted combine of the K expert outputs + classifier MLP.
// ---------------------------------------------------------------------------
__global__ __launch_bounds__(64) void k_final(const float* __restrict__ eo,
                                              const float* __restrict__ sel_w,
                                              const float* __restrict__ cw1,
                                              const float* __restrict__ cb1,
                                              const float* __restrict__ cw2,
                                              const float* __restrict__ cb2,
                                              float* __restrict__ out_logits) {
  int b = blockIdx.x * blockDim.x + threadIdx.x;
  if (b >= B_) return;
  float feat[O_];
  float w0 = sel_w[b * K_ + 0], w1 = sel_w[b * K_ + 1], w2 = sel_w[b * K_ + 2];
  const float* e0 = eo + (size_t)(b * K_ + 0) * O_;
  const float* e1 = eo + (size_t)(b * K_ + 1) * O_;
  const float* e2 = eo + (size_t)(b * K_ + 2) * O_;
  for (int o = 0; o < O_; ++o)
    feat[o] = w0 * e0[o] + w1 * e1[o] + w2 * e2[o];

  float ch[CH_];
  for (int jj = 0; jj < CH_; ++jj) {
    float a = cb1[jj];
    for (int o = 0; o < O_; ++o) a = fmaf(feat[o], cw1[o * CH_ + jj], a);
    ch[jj] = fmaxf(a, 0.f);
  }
  for (int c = 0; c < C_; ++c) {
    float a = cb2[c];
    for (int jj = 0; jj < CH_; ++jj) a = fmaf(ch[jj], cw2[jj * C_ + c], a);
    out_logits[(size_t)b * C_ + c] = a;
  }
}

// ---------------------------------------------------------------------------
extern "C" void kernel_launch(void* const* d_in, const int* in_sizes, int n_in,
                              void* d_out, int out_size, void* d_ws, size_t ws_size,
                              hipStream_t stream) {
  const float* x_rna    = (const float*)d_in[0];
  const float* x_cnv    = (const float*)d_in[1];
  const float* x_met    = (const float*)d_in[2];
  const float* gene_mask= (const float*)d_in[3];
  const float* gate_w1  = (const float*)d_in[4];
  const float* gate_b1  = (const float*)d_in[5];
  const float* gate_w2  = (const float*)d_in[6];
  const float* gate_b2  = (const float*)d_in[7];
  const float* W1       = (const float*)d_in[8];
  const float* b1       = (const float*)d_in[9];
  const float* bn_g     = (const float*)d_in[10];
  const float* bn_b     = (const float*)d_in[11];
  const float* bn_m     = (const float*)d_in[12];
  const float* bn_v     = (const float*)d_in[13];
  const float* W2       = (const float*)d_in[14];
  const float* b2       = (const float*)d_in[15];
  const float* cls_w1   = (const float*)d_in[16];
  const float* cls_b1   = (const float*)d_in[17];
  const float* cls_w2   = (const float*)d_in[18];
  const float* cls_b2   = (const float*)d_in[19];

  float* out_logits = (float*)d_out;                   // [B, C]
  float* out_gw     = (float*)d_out + (size_t)B_ * C_; // [B, P]

  // workspace layout (bytes)
  char* ws = (char*)d_ws;
  int*   cnt     = (int*)(ws + 0);                 // 512
  int*   gindex  = (int*)(ws + 512);               // 128*4000*4 = 2,048,000
  int*   sel_idx = (int*)(ws + 2048512);           // 3072
  float* sel_w   = (float*)(ws + 2051584);         // 3072
  float* eo      = (float*)(ws + 2054656);         // 49152
  unsigned short* wcomp = (unsigned short*)(ws + 2103808); // 128*3*640*64*2 = 31.5MB

  hipLaunchKernelGGL(k_pre, dim3(P_ + B_), dim3(512), 0, stream,
                     gene_mask, x_rna, gate_w1, gate_b1, gate_w2, gate_b2,
                     cnt, gindex, out_gw, sel_idx, sel_w);
  hipLaunchKernelGGL(k_copy, dim3(P_ * 8), dim3(256), 0, stream,
                     W1, cnt, gindex, wcomp);
  hipLaunchKernelGGL(k_expert, dim3(B_ * K_), dim3(512), 0, stream,
                     x_rna, x_cnv, x_met, W1, b1, bn_g, bn_b, bn_m, bn_v,
                     W2, b2, cnt, gindex, wcomp, sel_idx, eo);
  hipLaunchKernelGGL(k_final, dim3((B_ + 63) / 64), dim3(64), 0, stream,
                     eo, sel_w, cls_w1, cls_b1, cls_w2, cls_b2, out_logits);
}

// Round 11
// 69.562 us; speedup vs baseline: 1.4015x; 1.2133x over previous
//
#include <hip/hip_runtime.h>
#include <hip/hip_bf16.h>
#include <math.h>

#define B_ 256
#define G_ 4000
#define P_ 128
#define D_ 12000
#define H_ 64
#define O_ 16
#define GH_ 128
#define CH_ 8
#define C_ 5
#define K_ 3
#define EPS_ 1e-5f
#define KCH_ 500    // gate gemm1: K-chunk per tile
#define KIN_ 100    // gate gemm1: inner K tile in LDS
#define CAP_ 640    // compacted row capacity per pathway (n_p ~ 400 +- 20)
#define TILE_ 640   // expert gene tile (covers n<=CAP_ in one pass)

__device__ __forceinline__ float bf_lo(unsigned int u) {
  return __uint_as_float(u << 16);
}
__device__ __forceinline__ float bf_hi(unsigned int u) {
  return __uint_as_float(u & 0xffff0000u);
}

// ---------------------------------------------------------------------------
// K1 (R5-proven): blocks [0,128) = per-pathway compaction;
//                 blocks [128,384) = gate GEMM1 partial tiles -> hpart.
// ---------------------------------------------------------------------------
__global__ __launch_bounds__(512) void k_pre(const float* __restrict__ gene_mask,
                                             const float* __restrict__ x_rna,
                                             const float* __restrict__ gw1,
                                             int* __restrict__ cnt,
                                             int* __restrict__ gindex,
                                             float* __restrict__ hpart) {
  int t = threadIdx.x;

  if (blockIdx.x < P_) {
    int p = blockIdx.x;
    int lane = t & 63;
    int w = t >> 6;
    __shared__ int wcnt[8];
    int* lp = gindex + (size_t)p * G_;
    const int per = (G_ + 7) / 8;   // 500
    int start = w * per;
    int end = start + per; if (end > G_) end = G_;

    int count = 0;
    for (int g0 = start; g0 < end; g0 += 64) {
      int g = g0 + lane;
      bool act = (g < end) && (gene_mask[(size_t)g * P_ + p] != 0.0f);
      count += __popcll(__ballot(act));
    }
    if (lane == 0) wcnt[w] = count;
    __syncthreads();
    if (t == 0) {
      int tot = 0;
      for (int i = 0; i < 8; ++i) tot += wcnt[i];
      cnt[p] = tot;
    }
    int base = 0;
    for (int i = 0; i < w; ++i) base += wcnt[i];
    for (int g0 = start; g0 < end; g0 += 64) {
      int g = g0 + lane;
      bool act = (g < end) && (gene_mask[(size_t)g * P_ + p] != 0.0f);
      unsigned long long bal = __ballot(act);
      int rank = __popcll(bal & ((1ull << lane) - 1ull));
      if (act) lp[base + rank] = g;
      base += __popcll(bal);
    }
    return;
  }

  // ---- gate GEMM1 partial tile ----
  int idx = blockIdx.x - P_;        // 0..255
  int bt = idx >> 5;                // 8 b-tiles of 32
  int sub = idx & 31;
  int jt = sub >> 3;                // 4 j-tiles of 32
  int kc = sub & 7;                 // 8 k-chunks of 500
  int b0 = bt * 32;
  int j0 = jt * 32;

  __shared__ float xa[32 * KIN_];
  __shared__ float wa[KIN_ * 32];
  float2* wa2 = (float2*)wa;

  int bi = t >> 4;
  int jp = t & 15;
  float2 acc = {0.f, 0.f};

  for (int ch = 0; ch < KCH_ / KIN_; ++ch) {
    int kb = kc * KCH_ + ch * KIN_;
    __syncthreads();
    for (int id = t; id < 32 * KIN_; id += 512) {
      int r = id / KIN_, c = id - r * KIN_;
      xa[id] = x_rna[(size_t)(b0 + r) * G_ + kb + c];
    }
    for (int id = t; id < KIN_ * 32; id += 512) {
      int r = id >> 5, c = id & 31;
      wa[id] = gw1[(size_t)(kb + r) * GH_ + j0 + c];
    }
    __syncthreads();
#pragma unroll 4
    for (int kk = 0; kk < KIN_; ++kk) {
      float x = xa[bi * KIN_ + kk];
      float2 w = wa2[kk * 16 + jp];
      acc.x = fmaf(x, w.x, acc.x);
      acc.y = fmaf(x, w.y, acc.y);
    }
  }
  float2* out = (float2*)(hpart + ((size_t)kc * B_ + (b0 + bi)) * GH_ + j0 + jp * 2);
  *out = acc;
}

// ---------------------------------------------------------------------------
// K2: grid-branched.
//   blocks [0,256):   gate combine + GEMM2 + wave-parallel top-3 + sigmoid.
//   blocks [256,768): W1 -> dense bf16 planes wcomp[p][omic][gi][h]
//                     (512 blocks = pathway x quarter; 8 waves each).
// ---------------------------------------------------------------------------
__global__ __launch_bounds__(512) void k_gate2copy(const float* __restrict__ hpart,
                                                   const float* __restrict__ gb1,
                                                   const float* __restrict__ gw2,
                                                   const float* __restrict__ gb2,
                                                   const float* __restrict__ W1,
                                                   const int* __restrict__ cnt,
                                                   const int* __restrict__ gindex,
                                                   unsigned short* __restrict__ wcomp,
                                                   float* __restrict__ out_gw,
                                                   int* __restrict__ sel_idx,
                                                   float* __restrict__ sel_w) {
  int t = threadIdx.x;

  if (blockIdx.x < 256) {
    int b = blockIdx.x;
    __shared__ float hid[GH_];
    __shared__ float logitS[P_];
    __shared__ int   s_idx[K_];
    __shared__ float s_val[K_];

    if (t < GH_) {
      float s = gb1[t];
      for (int kc = 0; kc < 8; ++kc)
        s += hpart[((size_t)kc * B_ + b) * GH_ + t];
      hid[t] = fmaxf(s, 0.f);
    }
    __syncthreads();

    if (t < P_) {
      float acc = gb2[t];
      for (int jj = 0; jj < GH_; ++jj)
        acc = fmaf(hid[jj], gw2[(size_t)jj * P_ + t], acc);
      logitS[t] = acc;
    }
    __syncthreads();

    if (t < 64) {
      float v0 = logitS[t], v1 = logitS[t + 64];
      int i0 = t, i1 = t + 64;
      for (int k = 0; k < K_; ++k) {
        float v; int i;
        if (v0 > v1 || (v0 == v1 && i0 < i1)) { v = v0; i = i0; }
        else                                  { v = v1; i = i1; }
        for (int sft = 1; sft < 64; sft <<= 1) {
          float ov = __shfl_xor(v, sft);
          int   oi = __shfl_xor(i, sft);
          if (ov > v || (ov == v && oi < i)) { v = ov; i = oi; }
        }
        if (t == 0) {
          float w = 1.f / (1.f + expf(-v));
          s_idx[k] = i; s_val[k] = w;
          sel_idx[b * K_ + k] = i;
          sel_w[b * K_ + k] = w;
        }
        if (i0 == i) v0 = -INFINITY;
        if (i1 == i) v1 = -INFINITY;
      }
    }
    __syncthreads();

    if (t < P_) {
      float gwv = 0.f;
      for (int k = 0; k < K_; ++k) if (s_idx[k] == t) gwv = s_val[k];
      out_gw[(size_t)b * P_ + t] = gwv;
    }
    return;
  }

  // ---- W1 -> bf16 planes ----
  int cb = blockIdx.x - 256;        // 0..511
  int p = cb >> 2;
  int q = cb & 3;
  int n = cnt[p];
  if (n > CAP_) n = CAP_;           // overflow handled by expert f32 tail
  int per = (n + 3) / 4;
  int r0 = q * per, r1 = r0 + per;
  if (r1 > n) r1 = n;
  if (r0 >= r1) return;
  int lane = t & 63;
  int w = t >> 6;                   // 0..7
  const int* gp = gindex + (size_t)p * G_;
#pragma unroll
  for (int o = 0; o < 3; ++o) {
    const float* src = W1 + ((size_t)p * D_ + (size_t)o * G_) * H_;
    unsigned short* dst = wcomp + (size_t)(p * 3 + o) * CAP_ * H_;
    for (int gi = r0 + w; gi < r1; gi += 8) {
      int g = gp[gi];
      float f = src[(size_t)g * H_ + lane];
      __hip_bfloat16 bv = __float2bfloat16(f);
      dst[(size_t)gi * H_ + lane] = *(unsigned short*)&bv;
    }
  }
}

// ---------------------------------------------------------------------------
// K3: expert, one block (8 waves) per (sample, pathway) selection.
// Lane = (go=gene-octet 0..7, ho=h-octet 0..7); each uint4 wave-load covers
// 8 contiguous rows x 128B = 1KB of one omic plane (half the load
// instructions of the float4 version). acc[8] per lane (h = ho*8+q).
// Partials -> part[64][H+4] -> reduce -> BN+ReLU -> W2 -> eo[bk].
// ---------------------------------------------------------------------------
__global__ __launch_bounds__(512) void k_expert(const float* __restrict__ xr,
                                                const float* __restrict__ xc,
                                                const float* __restrict__ xm,
                                                const float* __restrict__ W1,
                                                const float* __restrict__ b1,
                                                const float* __restrict__ bn_g,
                                                const float* __restrict__ bn_b,
                                                const float* __restrict__ bn_m,
                                                const float* __restrict__ bn_v,
                                                const float* __restrict__ W2,
                                                const float* __restrict__ b2,
                                                const int* __restrict__ cnt,
                                                const int* __restrict__ gindex,
                                                const unsigned short* __restrict__ wcomp,
                                                const int* __restrict__ sel_idx,
                                                float* __restrict__ eo) {
  int bk = blockIdx.x;              // 768 blocks
  int b = bk / K_;
  int t = threadIdx.x;
  int w = t >> 6;                   // wave 0..7
  int lane = t & 63;
  int go = lane >> 3;               // gene octet slot 0..7
  int ho = lane & 7;                // h-octet: h = ho*8..ho*8+7
  int p = sel_idx[bk];
  int n = cnt[p];
  const int* gp = gindex + (size_t)p * G_;
  const unsigned short* Wp = wcomp + (size_t)(p * 3) * CAP_ * H_;
  const float* xrb = xr + (size_t)b * G_;
  const float* xcb = xc + (size_t)b * G_;
  const float* xmb = xm + (size_t)b * G_;

  __shared__ int   glist[TILE_];
  __shared__ float xv0[TILE_], xv1[TILE_], xv2[TILE_];
  __shared__ float part[64][H_ + 4];   // ~17.4 KB
  __shared__ float hs[H_];

  float acc[8];
#pragma unroll
  for (int q = 0; q < 8; ++q) acc[q] = 0.f;

  for (int t0 = 0; t0 < n; t0 += TILE_) {
    int m = n - t0; if (m > TILE_) m = TILE_;
    __syncthreads();
    for (int i = t; i < m; i += 512) {
      int g = gp[t0 + i];
      glist[i] = g;
      xv0[i] = xrb[g]; xv1[i] = xcb[g]; xv2[i] = xmb[g];
    }
    __syncthreads();
    int mfast = CAP_ - t0;
    if (mfast > m) mfast = m;
    if (mfast < 0) mfast = 0;
    // wave w covers genes w*8+go + 64*it
    for (int i0 = w * 8 + go; i0 < mfast; i0 += 64) {
      size_t off = (size_t)(t0 + i0) * H_ + ho * 8;
      uint4 u0 = *(const uint4*)(Wp + off);
      uint4 u1 = *(const uint4*)(Wp + (size_t)CAP_ * H_ + off);
      uint4 u2 = *(const uint4*)(Wp + (size_t)2 * CAP_ * H_ + off);
      float x0 = xv0[i0], x1 = xv1[i0], x2 = xv2[i0];
      acc[0] = fmaf(x0, bf_lo(u0.x), acc[0]); acc[1] = fmaf(x0, bf_hi(u0.x), acc[1]);
      acc[2] = fmaf(x0, bf_lo(u0.y), acc[2]); acc[3] = fmaf(x0, bf_hi(u0.y), acc[3]);
      acc[4] = fmaf(x0, bf_lo(u0.z), acc[4]); acc[5] = fmaf(x0, bf_hi(u0.z), acc[5]);
      acc[6] = fmaf(x0, bf_lo(u0.w), acc[6]); acc[7] = fmaf(x0, bf_hi(u0.w), acc[7]);
      acc[0] = fmaf(x1, bf_lo(u1.x), acc[0]); acc[1] = fmaf(x1, bf_hi(u1.x), acc[1]);
      acc[2] = fmaf(x1, bf_lo(u1.y), acc[2]); acc[3] = fmaf(x1, bf_hi(u1.y), acc[3]);
      acc[4] = fmaf(x1, bf_lo(u1.z), acc[4]); acc[5] = fmaf(x1, bf_hi(u1.z), acc[5]);
      acc[6] = fmaf(x1, bf_lo(u1.w), acc[6]); acc[7] = fmaf(x1, bf_hi(u1.w), acc[7]);
      acc[0] = fmaf(x2, bf_lo(u2.x), acc[0]); acc[1] = fmaf(x2, bf_hi(u2.x), acc[1]);
      acc[2] = fmaf(x2, bf_lo(u2.y), acc[2]); acc[3] = fmaf(x2, bf_hi(u2.y), acc[3]);
      acc[4] = fmaf(x2, bf_lo(u2.z), acc[4]); acc[5] = fmaf(x2, bf_hi(u2.z), acc[5]);
      acc[6] = fmaf(x2, bf_lo(u2.w), acc[6]); acc[7] = fmaf(x2, bf_hi(u2.w), acc[7]);
    }
    if (mfast < m) {
      // overflow tail (n > CAP_, ~never): f32 gather in the SAME lane layout
      const float* W1p = W1 + (size_t)p * D_ * H_;
      for (int i0 = w * 8 + go; i0 < m; i0 += 64) {
        if (i0 < mfast) continue;
        int g = glist[i0];
        const float* r = W1p + (size_t)g * H_ + ho * 8;
        float x0 = xv0[i0], x1 = xv1[i0], x2 = xv2[i0];
        float4 p0 = *(const float4*)r;
        float4 p1 = *(const float4*)(r + 4);
        acc[0] = fmaf(x0, p0.x, acc[0]); acc[1] = fmaf(x0, p0.y, acc[1]);
        acc[2] = fmaf(x0, p0.z, acc[2]); acc[3] = fmaf(x0, p0.w, acc[3]);
        acc[4] = fmaf(x0, p1.x, acc[4]); acc[5] = fmaf(x0, p1.y, acc[5]);
        acc[6] = fmaf(x0, p1.z, acc[6]); acc[7] = fmaf(x0, p1.w, acc[7]);
        const float* r1p = r + (size_t)G_ * H_;
        p0 = *(const float4*)r1p; p1 = *(const float4*)(r1p + 4);
        acc[0] = fmaf(x1, p0.x, acc[0]); acc[1] = fmaf(x1, p0.y, acc[1]);
        acc[2] = fmaf(x1, p0.z, acc[2]); acc[3] = fmaf(x1, p0.w, acc[3]);
        acc[4] = fmaf(x1, p1.x, acc[4]); acc[5] = fmaf(x1, p1.y, acc[5]);
        acc[6] = fmaf(x1, p1.z, acc[6]); acc[7] = fmaf(x1, p1.w, acc[7]);
        const float* r2p = r + (size_t)(2 * G_) * H_;
        p0 = *(const float4*)r2p; p1 = *(const float4*)(r2p + 4);
        acc[0] = fmaf(x2, p0.x, acc[0]); acc[1] = fmaf(x2, p0.y, acc[1]);
        acc[2] = fmaf(x2, p0.z, acc[2]); acc[3] = fmaf(x2, p0.w, acc[3]);
        acc[4] = fmaf(x2, p1.x, acc[4]); acc[5] = fmaf(x2, p1.y, acc[5]);
        acc[6] = fmaf(x2, p1.z, acc[6]); acc[7] = fmaf(x2, p1.w, acc[7]);
      }
    }
  }
  {
    float4 av0 = {acc[0], acc[1], acc[2], acc[3]};
    float4 av1 = {acc[4], acc[5], acc[6], acc[7]};
    *(float4*)&part[w * 8 + go][ho * 8] = av0;
    *(float4*)&part[w * 8 + go][ho * 8 + 4] = av1;
  }
  __syncthreads();

  if (t < H_) {
    float s = 0.f;
#pragma unroll
    for (int ss = 0; ss < 64; ++ss) s += part[ss][t];
    int ph = p * H_ + t;
    s += b1[ph];
    float hn = (s - bn_m[ph]) * (bn_g[ph] * rsqrtf(bn_v[ph] + EPS_)) + bn_b[ph];
    hs[t] = fmaxf(hn, 0.f);
  }
  __syncthreads();

  if (t < O_) {
    const float* W2p = W2 + (size_t)p * H_ * O_;
    float o = b2[p * O_ + t];
    for (int jj = 0; jj < H_; ++jj) o = fmaf(hs[jj], W2p[jj * O_ + t], o);
    eo[(size_t)bk * O_ + t] = o;
  }
}

// ---------------------------------------------------------------------------
// K4: weighted combine of the K expert outputs + classifier MLP.
// ---------------------------------------------------------------------------
__global__ __launch_bounds__(64) void k_final(const float* __restrict__ eo,
                                              const float* __restrict__ sel_w,
                                              const float* __restrict__ cw1,
                                              const float* __restrict__ cb1,
                                              const float* __restrict__ cw2,
                                              const float* __restrict__ cb2,
                                              float* __restrict__ out_logits) {
  int b = blockIdx.x * blockDim.x + threadIdx.x;
  if (b >= B_) return;
  float feat[O_];
  float w0 = sel_w[b * K_ + 0], w1 = sel_w[b * K_ + 1], w2 = sel_w[b * K_ + 2];
  const float* e0 = eo + (size_t)(b * K_ + 0) * O_;
  const float* e1 = eo + (size_t)(b * K_ + 1) * O_;
  const float* e2 = eo + (size_t)(b * K_ + 2) * O_;
  for (int o = 0; o < O_; ++o)
    feat[o] = w0 * e0[o] + w1 * e1[o] + w2 * e2[o];

  float ch[CH_];
  for (int jj = 0; jj < CH_; ++jj) {
    float a = cb1[jj];
    for (int o = 0; o < O_; ++o) a = fmaf(feat[o], cw1[o * CH_ + jj], a);
    ch[jj] = fmaxf(a, 0.f);
  }
  for (int c = 0; c < C_; ++c) {
    float a = cb2[c];
    for (int jj = 0; jj < CH_; ++jj) a = fmaf(ch[jj], cw2[jj * C_ + c], a);
    out_logits[(size_t)b * C_ + c] = a;
  }
}

// ---------------------------------------------------------------------------
extern "C" void kernel_launch(void* const* d_in, const int* in_sizes, int n_in,
                              void* d_out, int out_size, void* d_ws, size_t ws_size,
                              hipStream_t stream) {
  const float* x_rna    = (const float*)d_in[0];
  const float* x_cnv    = (const float*)d_in[1];
  const float* x_met    = (const float*)d_in[2];
  const float* gene_mask= (const float*)d_in[3];
  const float* gate_w1  = (const float*)d_in[4];
  const float* gate_b1  = (const float*)d_in[5];
  const float* gate_w2  = (const float*)d_in[6];
  const float* gate_b2  = (const float*)d_in[7];
  const float* W1       = (const float*)d_in[8];
  const float* b1       = (const float*)d_in[9];
  const float* bn_g     = (const float*)d_in[10];
  const float* bn_b     = (const float*)d_in[11];
  const float* bn_m     = (const float*)d_in[12];
  const float* bn_v     = (const float*)d_in[13];
  const float* W2       = (const float*)d_in[14];
  const float* b2       = (const float*)d_in[15];
  const float* cls_w1   = (const float*)d_in[16];
  const float* cls_b1   = (const float*)d_in[17];
  const float* cls_w2   = (const float*)d_in[18];
  const float* cls_b2   = (const float*)d_in[19];

  float* out_logits = (float*)d_out;                   // [B, C]
  float* out_gw     = (float*)d_out + (size_t)B_ * C_; // [B, P]

  // workspace layout (bytes)
  char* ws = (char*)d_ws;
  int*   cnt     = (int*)(ws + 0);                 // 512
  int*   gindex  = (int*)(ws + 512);               // 2,048,000
  int*   sel_idx = (int*)(ws + 2048512);           // 3072
  float* sel_w   = (float*)(ws + 2051584);         // 3072
  float* eo      = (float*)(ws + 2054656);         // 49,152
  float* hpart   = (float*)(ws + 2103808);         // 1,048,576
  unsigned short* wcomp = (unsigned short*)(ws + 3152384); // 31,457,280

  hipLaunchKernelGGL(k_pre, dim3(P_ + 256), dim3(512), 0, stream,
                     gene_mask, x_rna, gate_w1, cnt, gindex, hpart);
  hipLaunchKernelGGL(k_gate2copy, dim3(768), dim3(512), 0, stream,
                     hpart, gate_b1, gate_w2, gate_b2, W1, cnt, gindex,
                     wcomp, out_gw, sel_idx, sel_w);
  hipLaunchKernelGGL(k_expert, dim3(B_ * K_), dim3(512), 0, stream,
                     x_rna, x_cnv, x_met, W1, b1, bn_g, bn_b, bn_m, bn_v,
                     W2, b2, cnt, gindex, wcomp, sel_idx, eo);
  hipLaunchKernelGGL(k_final, dim3((B_ + 63) / 64), dim3(64), 0, stream,
                     eo, sel_w, cls_w1, cls_b1, cls_w2, cls_b2, out_logits);
}